// Round 1
// baseline (44.920 us; speedup 1.0000x reference)
//
#include <hip/hip_runtime.h>

#define NLOC 100
#define BLK_PIX 1024
#define THREADS 256

// ws layout: [B*NLOC] uint minbits | [B*NLOC] float weights | [B] int ncflag

__global__ __launch_bounds__(256)
void k_init_weights(const float* __restrict__ prob, const float* __restrict__ unc,
                    unsigned* __restrict__ minb, float* __restrict__ wts,
                    int* __restrict__ ncflag, int P)
{
    const int b = blockIdx.x;
    const int tid = threadIdx.x;
    // init min-distance accumulators (atomicMin targets) to a huge positive float
    if (tid < NLOC) minb[b * NLOC + tid] = 0x7F7F7F7Fu;  // ~3.39e38f
    // wave 0: ordered scan for the first NLOC confident pixels (row-major order)
    if (tid < 64) {
        const int lane = tid;
        const float* probp = prob + (size_t)b * P;
        const float* up = unc + (size_t)b * P;
        const int nchunks = (P + 63) >> 6;
        int nconf = 0;
        for (int c = 0; c < nchunks; ++c) {
            if (nconf >= NLOC) break;
            int p = (c << 6) + lane;
            bool inb = p < P;
            float pv = probp[inb ? p : 0];
            bool conf = inb && (pv > 0.5f);
            unsigned long long mask = __ballot(conf);
            int pref = __popcll(mask & ((1ull << lane) - 1ull));
            int r = nconf + pref;
            if (conf && r < NLOC) wts[b * NLOC + r] = expf(-up[p]);
            nconf += __popcll(mask);
        }
        // general fallback (torch quirk): if fewer than NLOC confident pixels,
        // ranks continue into the non-confident pixels in row-major order.
        if (nconf < NLOC) {
            int nnon = 0;
            for (int c = 0; c < nchunks; ++c) {
                if (nconf + nnon >= NLOC) break;
                int p = (c << 6) + lane;
                bool inb = p < P;
                float pv = probp[inb ? p : 0];
                bool nonc = inb && !(pv > 0.5f);
                unsigned long long mask = __ballot(nonc);
                int pref = __popcll(mask & ((1ull << lane) - 1ull));
                int r = nconf + nnon + pref;
                if (nonc && r < NLOC) wts[b * NLOC + r] = expf(-up[p]);
                nnon += __popcll(mask);
            }
        }
        if (lane == 0) ncflag[b] = (nconf > 0) ? 1 : 0;
    }
}

__global__ __launch_bounds__(THREADS)
void k_min(const float* __restrict__ loc, const float* __restrict__ prob,
           const float* __restrict__ tloc, unsigned* __restrict__ minb, int P)
{
    __shared__ float2 s_pix[BLK_PIX];
    __shared__ float2 s_t[NLOC];
    __shared__ int s_cnt;
    const int b = blockIdx.y;
    const int base = blockIdx.x * BLK_PIX;
    const int tid = threadIdx.x;
    const int lane = tid & 63;
    if (tid == 0) s_cnt = 0;
    if (tid < NLOC) s_t[tid] = reinterpret_cast<const float2*>(tloc)[b * NLOC + tid];
    __syncthreads();
    const float2* locp = reinterpret_cast<const float2*>(loc) + (size_t)b * P;
    const float* probp = prob + (size_t)b * P;
    // stage: compact confident pixels into LDS (order irrelevant for min)
    #pragma unroll
    for (int i = 0; i < BLK_PIX / THREADS; ++i) {
        int p = base + tid + i * THREADS;
        bool inb = p < P;
        float pv = inb ? probp[p] : 0.0f;
        float2 xy = inb ? locp[p] : make_float2(0.f, 0.f);
        bool conf = inb && (pv > 0.5f);
        unsigned long long mask = __ballot(conf);
        int cnt = __popcll(mask);
        int pref = __popcll(mask & ((1ull << lane) - 1ull));
        int wb = 0;
        if (lane == 0 && cnt) wb = atomicAdd(&s_cnt, cnt);
        wb = __shfl(wb, 0);
        if (conf) s_pix[wb + pref] = xy;
    }
    __syncthreads();
    const int cnt = s_cnt;
    const int padded = (cnt + 255) & ~255;
    // sentinel pad so the inner loop is uniform and 4-way unrolled;
    // (1e15)^2*2 = 2e30 always loses to any real distance, never overflows
    for (int i = cnt + tid; i < padded; i += THREADS)
        s_pix[i] = make_float2(1.0e15f, 1.0e15f);
    __syncthreads();
    // each wave owns locs {wv, wv+4, ...}; no cross-wave reduce needed
    const int wv = tid >> 6;
    for (int n = wv; n < NLOC; n += THREADS / 64) {
        const float bx = s_t[n].x, by = s_t[n].y;
        float m0 = 3.0e38f, m1 = 3.0e38f, m2 = 3.0e38f, m3 = 3.0e38f;
        for (int i = lane; i < padded; i += 256) {
            float2 a0 = s_pix[i];
            float2 a1 = s_pix[i + 64];
            float2 a2 = s_pix[i + 128];
            float2 a3 = s_pix[i + 192];
            float dx0 = a0.x - bx, dy0 = a0.y - by;
            float dx1 = a1.x - bx, dy1 = a1.y - by;
            float dx2 = a2.x - bx, dy2 = a2.y - by;
            float dx3 = a3.x - bx, dy3 = a3.y - by;
            m0 = fminf(m0, dx0 * dx0 + dy0 * dy0);
            m1 = fminf(m1, dx1 * dx1 + dy1 * dy1);
            m2 = fminf(m2, dx2 * dx2 + dy2 * dy2);
            m3 = fminf(m3, dx3 * dx3 + dy3 * dy3);
        }
        float m = fminf(fminf(m0, m1), fminf(m2, m3));
        #pragma unroll
        for (int off = 32; off; off >>= 1)
            m = fminf(m, __shfl_xor(m, off));
        if (lane == 0)
            atomicMin(&minb[b * NLOC + n], __float_as_uint(m));  // d2>=0: uint order == float order
    }
}

__global__ void k_final(const float* __restrict__ tloc, const unsigned* __restrict__ minb,
                        const float* __restrict__ wts, const int* __restrict__ ncflag,
                        float* __restrict__ out, int B)
{
    __shared__ int s_wcnt[16][2];
    __shared__ float s_part[16][2];
    const int t = (int)threadIdx.x;
    const int b = t >> 7;          // 128 threads (2 waves) per batch
    const int j = t & 127;         // true-loc index
    const int lane = t & 63;
    const int wh = (t >> 6) & 1;   // which wave within the batch
    bool valid = false;
    if (j < NLOC) {
        float tx = tloc[((size_t)b * NLOC + j) * 2];
        float ty = tloc[((size_t)b * NLOC + j) * 2 + 1];
        valid = (tx >= 0.f) && (ty >= 0.f);
    }
    unsigned long long mask = __ballot(valid);
    int pref = __popcll(mask & ((1ull << lane) - 1ull));
    int wcnt = __popcll(mask);
    if (lane == 0) s_wcnt[b][wh] = wcnt;
    __syncthreads();
    int rank = pref + (wh ? s_wcnt[b][0] : 0);   // cumsum(valid)-1 for valid entries
    float contrib = 0.f;
    if (valid)
        contrib = sqrtf(__uint_as_float(minb[b * NLOC + j])) * wts[b * NLOC + rank];
    #pragma unroll
    for (int off = 32; off; off >>= 1)
        contrib += __shfl_xor(contrib, off);
    if (lane == 0) s_part[b][wh] = contrib;
    __syncthreads();
    if (t < 64) {
        float v = 0.f;
        if (lane < B) {
            int nv = s_wcnt[lane][0] + s_wcnt[lane][1];
            float sum = s_part[lane][0] + s_part[lane][1];
            v = (nv == 0) ? 0.f : ((ncflag[lane] == 0) ? 10.0f : sum / (float)nv);
        }
        #pragma unroll
        for (int off = 32; off; off >>= 1)
            v += __shfl_xor(v, off);
        if (t == 0) out[0] = v / (float)B;
    }
}

extern "C" void kernel_launch(void* const* d_in, const int* in_sizes, int n_in,
                              void* d_out, int out_size, void* d_ws, size_t ws_size,
                              hipStream_t stream)
{
    const float* loc  = (const float*)d_in[0];   // [B,H,W,2]
    const float* unc  = (const float*)d_in[1];   // [B,H,W,1]
    const float* tloc = (const float*)d_in[2];   // [B,N,2]
    const float* prob = (const float*)d_in[3];   // [B,1,H,W]
    float* out = (float*)d_out;

    const int B = in_sizes[2] / (2 * NLOC);
    const int P = in_sizes[1] / B;

    unsigned* minb = (unsigned*)d_ws;
    float* wts = (float*)((char*)d_ws + (size_t)B * NLOC * sizeof(unsigned));
    int* ncflag = (int*)((char*)d_ws + (size_t)2 * B * NLOC * sizeof(unsigned));

    hipLaunchKernelGGL(k_init_weights, dim3(B), dim3(256), 0, stream,
                       prob, unc, minb, wts, ncflag, P);
    const int nblk = (P + BLK_PIX - 1) / BLK_PIX;
    hipLaunchKernelGGL(k_min, dim3(nblk, B), dim3(THREADS), 0, stream,
                       loc, prob, tloc, minb, P);
    hipLaunchKernelGGL(k_final, dim3(1), dim3(B * 128), 0, stream,
                       tloc, minb, wts, ncflag, out, B);
}